// Round 2
// baseline (4784.491 us; speedup 1.0000x reference)
//
#include <hip/hip_runtime.h>
#include <hip/hip_bf16.h>

// MnistModelDP: 2-layer LSTM (H=512) over T=64 frames of 128, B=2048, then proj to 10.
// Strategy: fp16 MFMA (16x16x32) GEMMs with fp32 accumulate; cell update fused
// into GEMM epilogue (each thread owns i,f,g,o gates for its (row,col)).
// c kept fp32; h stored f16, double-buffered across steps.

typedef _Float16 f16x8 __attribute__((ext_vector_type(8)));
typedef float f32x4 __attribute__((ext_vector_type(4)));

#define Bsz 2048
#define Lsz 8192
#define INsz 128
#define Hsz 512
#define Tsz 64

__global__ void cvt_f32_f16(const float* __restrict__ src, _Float16* __restrict__ dst, int n4) {
    int stride = gridDim.x * blockDim.x;
    for (int i = blockIdx.x * blockDim.x + threadIdx.x; i < n4; i += stride) {
        float4 v = ((const float4*)src)[i];
        union { _Float16 h[4]; ushort4 u; } o;
        o.h[0] = (_Float16)v.x; o.h[1] = (_Float16)v.y;
        o.h[2] = (_Float16)v.z; o.h[3] = (_Float16)v.w;
        ((ushort4*)dst)[i] = o.u;
    }
}

__device__ __forceinline__ float sigmoidf_(float x) {
    return 1.0f / (1.0f + expf(-x));
}

// One LSTM layer timestep: gates = A1 @ W1^T + A2 @ W2^T + bias  (A row-major [2048,K],
// W row-major [2048 (=4H gate rows), K]); then cell update.
// Block: 4 waves; tile = 128 rows x 32 gate-cols x 4 gates.
// Wave w: rows rowW..rowW+31 (2 frags), all 32 gate-cols (2 frags), 4 gates -> 16 acc frags.
// MFMA 16x16x32 f16 layouts (verified lineage: learn_hip m89/m91):
//   A frag: lane l, elem j -> A[l&15][(l>>4)*8 + j]
//   B frag: lane l, elem j -> B[k=(l>>4)*8+j][col=l&15] = W[col][k] (W row-major, K contig)
//   C/D:    lane l, reg r  -> C[(l>>4)*4 + r][l&15]
__global__ __launch_bounds__(256) void lstm_step(
    const _Float16* __restrict__ A1, int lda1, int K1,
    const _Float16* __restrict__ W1,  // [2048, K1]
    const _Float16* __restrict__ A2,  // [2048, 512]
    const _Float16* __restrict__ W2,  // [2048, 512]
    const float* __restrict__ bias,   // [2048] fp32
    float* __restrict__ c,            // [2048, 512] fp32, in/out
    _Float16* __restrict__ h_out)     // [2048, 512] f16
{
    const int lane = threadIdx.x & 63;
    const int w    = threadIdx.x >> 6;
    const int llo  = lane & 15;
    const int lhi  = lane >> 4;
    const int rowW = blockIdx.x * 128 + w * 32;
    const int gc0  = blockIdx.y * 32;

    f32x4 acc[4][2][2] = {};

    float bz[4][2];
#pragma unroll
    for (int g = 0; g < 4; ++g)
#pragma unroll
        for (int gi = 0; gi < 2; ++gi)
            bz[g][gi] = bias[512 * g + gc0 + 16 * gi + llo];

    const _Float16* As[2] = {A1, A2};
    const _Float16* Ws[2] = {W1, W2};
    const int ldas[2] = {lda1, 512};
    const int Ks[2]   = {K1, 512};

#pragma unroll
    for (int s = 0; s < 2; ++s) {
        const _Float16* A  = As[s];
        const _Float16* Wt = Ws[s];
        const int lda = ldas[s];
        const int K   = Ks[s];
        const int ldw = K;  // weights are [2048, K] row-major
        for (int k0 = 0; k0 < K; k0 += 32) {
            f16x8 a[2];
#pragma unroll
            for (int mi = 0; mi < 2; ++mi)
                a[mi] = *(const f16x8*)(A + (size_t)(rowW + 16 * mi + llo) * lda + k0 + lhi * 8);
            f16x8 b[4][2];
#pragma unroll
            for (int g = 0; g < 4; ++g)
#pragma unroll
                for (int gi = 0; gi < 2; ++gi)
                    b[g][gi] = *(const f16x8*)(Wt + (size_t)(512 * g + gc0 + 16 * gi + llo) * ldw + k0 + lhi * 8);
#pragma unroll
            for (int g = 0; g < 4; ++g)
#pragma unroll
                for (int mi = 0; mi < 2; ++mi)
#pragma unroll
                    for (int gi = 0; gi < 2; ++gi)
                        acc[g][mi][gi] = __builtin_amdgcn_mfma_f32_16x16x32_f16(
                            a[mi], b[g][gi], acc[g][mi][gi], 0, 0, 0);
        }
    }

    // fused cell update epilogue
#pragma unroll
    for (int mi = 0; mi < 2; ++mi) {
#pragma unroll
        for (int gi = 0; gi < 2; ++gi) {
            const int col = gc0 + 16 * gi + llo;
#pragma unroll
            for (int r = 0; r < 4; ++r) {
                const int row = rowW + 16 * mi + lhi * 4 + r;
                float iv = acc[0][mi][gi][r] + bz[0][gi];
                float fv = acc[1][mi][gi][r] + bz[1][gi];
                float gv = acc[2][mi][gi][r] + bz[2][gi];
                float ov = acc[3][mi][gi][r] + bz[3][gi];
                size_t idx = (size_t)row * 512 + col;
                float co = c[idx];
                float cn = sigmoidf_(fv) * co + sigmoidf_(iv) * tanhf(gv);
                float hn = sigmoidf_(ov) * tanhf(cn);
                c[idx] = cn;
                h_out[idx] = (_Float16)hn;
            }
        }
    }
}

__global__ void proj_kernel(const _Float16* __restrict__ h1,
                            const float* __restrict__ Wout,  // [10, 512]
                            const float* __restrict__ bout,  // [10]
                            float* __restrict__ out)         // [2048, 10]
{
    int tid = blockIdx.x * blockDim.x + threadIdx.x;
    if (tid >= Bsz * 10) return;
    int b = tid / 10, o = tid % 10;
    float s = bout[o];
    const _Float16* hrow = h1 + (size_t)b * 512;
    const float* wrow = Wout + (size_t)o * 512;
    for (int k = 0; k < 512; ++k) s += (float)hrow[k] * wrow[k];
    out[tid] = s;
}

extern "C" void kernel_launch(void* const* d_in, const int* in_sizes, int n_in,
                              void* d_out, int out_size, void* d_ws, size_t ws_size,
                              hipStream_t stream) {
    const float* xb    = (const float*)d_in[0];
    const float* W_ih0 = (const float*)d_in[1];
    const float* W_hh0 = (const float*)d_in[2];
    const float* b0    = (const float*)d_in[3];
    const float* W_ih1 = (const float*)d_in[4];
    const float* W_hh1 = (const float*)d_in[5];
    const float* b1    = (const float*)d_in[6];
    const float* W_out = (const float*)d_in[7];
    const float* b_out = (const float*)d_in[8];
    float* out = (float*)d_out;

    char* ws = (char*)d_ws;
    size_t off = 0;
    auto alloc = [&](size_t bytes) -> void* {
        void* p = ws + off;
        off += (bytes + 255) & ~(size_t)255;
        return p;
    };
    _Float16* xb16  = (_Float16*)alloc((size_t)Bsz * Lsz * 2);
    _Float16* wih0f = (_Float16*)alloc((size_t)2048 * 128 * 2);
    _Float16* whh0f = (_Float16*)alloc((size_t)2048 * 512 * 2);
    _Float16* wih1f = (_Float16*)alloc((size_t)2048 * 512 * 2);
    _Float16* whh1f = (_Float16*)alloc((size_t)2048 * 512 * 2);
    _Float16* h0b[2], * h1b[2];
    h0b[0] = (_Float16*)alloc((size_t)Bsz * Hsz * 2);
    h0b[1] = (_Float16*)alloc((size_t)Bsz * Hsz * 2);
    h1b[0] = (_Float16*)alloc((size_t)Bsz * Hsz * 2);
    h1b[1] = (_Float16*)alloc((size_t)Bsz * Hsz * 2);
    float* c0 = (float*)alloc((size_t)Bsz * Hsz * 4);
    float* c1 = (float*)alloc((size_t)Bsz * Hsz * 4);

    // convert inputs to f16
    cvt_f32_f16<<<1024, 256, 0, stream>>>(xb, xb16, Bsz * Lsz / 4);
    cvt_f32_f16<<<256, 256, 0, stream>>>(W_ih0, wih0f, 2048 * 128 / 4);
    cvt_f32_f16<<<512, 256, 0, stream>>>(W_hh0, whh0f, 2048 * 512 / 4);
    cvt_f32_f16<<<512, 256, 0, stream>>>(W_ih1, wih1f, 2048 * 512 / 4);
    cvt_f32_f16<<<512, 256, 0, stream>>>(W_hh1, whh1f, 2048 * 512 / 4);

    // zero initial state
    hipMemsetAsync(h0b[0], 0, (size_t)Bsz * Hsz * 2, stream);
    hipMemsetAsync(h1b[0], 0, (size_t)Bsz * Hsz * 2, stream);
    hipMemsetAsync(c0, 0, (size_t)Bsz * Hsz * 4, stream);
    hipMemsetAsync(c1, 0, (size_t)Bsz * Hsz * 4, stream);

    dim3 grid(16, 16);
    for (int t = 0; t < Tsz; ++t) {
        int rd = t & 1, wr = (t + 1) & 1;
        // layer 0: x_t (from xb16, row stride 8192, col offset t*128) + h0_prev
        lstm_step<<<grid, 256, 0, stream>>>(
            xb16 + (size_t)t * 128, Lsz, 128, wih0f,
            h0b[rd], whh0f, b0, c0, h0b[wr]);
        // layer 1: h0_new + h1_prev
        lstm_step<<<grid, 256, 0, stream>>>(
            h0b[wr], 512, 512, wih1f,
            h1b[rd], whh1f, b1, c1, h1b[wr]);
    }

    // final projection: h1 after step 63 lives in h1b[0]
    proj_kernel<<<(Bsz * 10 + 255) / 256, 256, 0, stream>>>(h1b[0], W_out, b_out, out);
}